// Round 4
// baseline (389.038 us; speedup 1.0000x reference)
//
#include <hip/hip_runtime.h>
#include <hip/hip_bf16.h>

typedef __bf16 bf16_t;
typedef __bf16 bf16x4 __attribute__((ext_vector_type(4)));
typedef __bf16 bf16x8 __attribute__((ext_vector_type(8)));
typedef float  f32x4  __attribute__((ext_vector_type(4)));

static __device__ __forceinline__ f32x4 mfma16(bf16x8 a, bf16x8 b, f32x4 c) {
  return __builtin_amdgcn_mfma_f32_16x16x32_bf16(a, b, c, 0, 0, 0);
}

typedef const __attribute__((address_space(1))) void* gas_t;
typedef __attribute__((address_space(3))) void* las_t;
#define ASYNC16(g, l) __builtin_amdgcn_global_load_lds((gas_t)(g), (las_t)(l), 16, 0, 0)

// Problem constants
#define QL_   512
#define HID_  4096
#define NH_   32
#define NKV_  8
#define HD_   128
#define PAST_ 3584
#define KVL_  4096   // PAST_ + QL_
#define NSPLIT 8     // attention kv-split factor

// Q prescale: log2(e)/sqrt(128) -> softmax via raw exp2, no max subtraction
#define QSCALE 0.12751750152134056f

// K fragment-layout index (kv-tiles of 64, MFMA B-operand contiguous)
static __device__ __forceinline__ size_t kidx(int s, int d) {
  return ((size_t)(((s >> 6) * 4 + ((s >> 4) & 3)) * 4 + (d >> 5))) * 512
         + ((((d >> 3) & 3) * 16 + (s & 15)) * 8) + (d & 7);
}
// V fragment-layout index (PV B-operand: out-col = d, contraction = kv)
static __device__ __forceinline__ size_t vidx(int s, int d) {
  return ((size_t)(((s >> 6) * 8 + (d >> 4)) * 2 + ((s >> 5) & 1))) * 512
         + (((((s >> 3) & 3) * 16 + (d & 15)) * 8)) + (s & 7);
}

// ======================================================================
// fp32 -> bf16 streaming convert (n4 = element count / 4)
// ======================================================================
__global__ __launch_bounds__(256) void cvt_f32_bf16(
    const float* __restrict__ src, bf16_t* __restrict__ dst, int n4)
{
  int i = blockIdx.x * 256 + threadIdx.x;
  const int stride = gridDim.x * 256;
  for (; i < n4; i += stride) {
    float4 f = ((const float4*)src)[i];
    bf16x4 o;
    o[0] = (bf16_t)f.x; o[1] = (bf16_t)f.y; o[2] = (bf16_t)f.z; o[3] = (bf16_t)f.w;
    ((bf16x4*)dst)[i] = o;
  }
}

// Fused convert: wq|wk|wv|hidden in ONE flat index space (load-balanced;
// the per-tensor-blockIdx.y version left 3/4 of the grid idle while the
// 64 MB wq segment finished).
__global__ __launch_bounds__(256) void cvt_multi(
    const float* __restrict__ swq, const float* __restrict__ swk,
    const float* __restrict__ swv, const float* __restrict__ shid,
    bf16_t* __restrict__ dwq, bf16_t* __restrict__ dwk,
    bf16_t* __restrict__ dwv, bf16_t* __restrict__ dhid)
{
  constexpr int N0 = 4096 * HID_ / 4;          // wq  : 4,194,304
  constexpr int N1 = N0 + 1024 * HID_ / 4;     // +wk : 5,242,880
  constexpr int N2 = N1 + 1024 * HID_ / 4;     // +wv : 6,291,456
  constexpr int N3 = N2 + QL_ * HID_ / 4;      // +hid: 6,815,744
  int i = blockIdx.x * 256 + threadIdx.x;
  const int stride = gridDim.x * 256;
  for (; i < N3; i += stride) {
    const float* src; bf16_t* dst; int off;
    if (i < N0)      { src = swq;  dst = dwq;  off = i; }
    else if (i < N1) { src = swk;  dst = dwk;  off = i - N0; }
    else if (i < N2) { src = swv;  dst = dwv;  off = i - N1; }
    else             { src = shid; dst = dhid; off = i - N2; }
    float4 f = ((const float4*)src)[off];
    bf16x4 o;
    o[0] = (bf16_t)f.x; o[1] = (bf16_t)f.y; o[2] = (bf16_t)f.z; o[3] = (bf16_t)f.w;
    ((bf16x4*)dst)[off] = o;
  }
}

// ======================================================================
// GEMM: C[M,N] = A[M,K] @ B[N,K]^T, bf16, global_load_lds staging.
// Depth-2 software pipeline (T4, counted vmcnt): 3 LDS buffers; per tile
//   s_waitcnt vmcnt(6)   -- retire tile t, leave tile t+1 in flight
//   s_barrier            -- publish tile t to all waves
//   stage(t+2)           -- issued with 2 compute phases to land
//   compute(t)
// Hazards: stage(t+2) overwrites tile t-1's buffer, whose readers all
// passed this barrier; each stage = exactly 6 vmem ops/wave so counts
// are exact. BM=64, BN=128, BK=64; 4 waves 2x2 (wave tile 32x64).
// LDS 72 KB -> 2 blocks/CU cap (grid is 1.5/CU anyway).
// ======================================================================
template<bool C_F32>
__global__ __launch_bounds__(256) void gemm_bt(
    const bf16_t* __restrict__ A,
    const bf16_t* __restrict__ B0, const bf16_t* __restrict__ B1,
    const bf16_t* __restrict__ B2, int nsplit1, int nsplit2,
    void* __restrict__ Cptr, int K, int lda, int ldb, int ldc)
{
  constexpr int BM = 64, BN = 128, BK = 64;
  __shared__ bf16_t As[3][BM * BK];   // 3 x 8 KB
  __shared__ bf16_t Bs[3][BN * BK];   // 3 x 16 KB

  const int tid = threadIdx.x;
  const int w = tid >> 6, lane = tid & 63;
  const int lm = lane & 15, quad = lane >> 4;
  const int wr = w >> 1, wc = w & 1;
  const int bm0 = blockIdx.y * BM, bn0 = blockIdx.x * BN;

  const bf16_t* Bseg; int bn_loc;
  if (bn0 < nsplit1)      { Bseg = B0; bn_loc = bn0; }
  else if (bn0 < nsplit2) { Bseg = B1; bn_loc = bn0 - nsplit1; }
  else                    { Bseg = B2; bn_loc = bn0 - nsplit2; }

  // staging units: A = 512 x 16B (2/thread), B = 1024 x 16B (4/thread)
  int sidA[2], rA[2], cA[2];
#pragma unroll
  for (int j = 0; j < 2; j++) {
    sidA[j] = j * 256 + tid;
    rA[j] = sidA[j] >> 3;
    cA[j] = ((sidA[j] & 7) ^ (rA[j] & 7)) * 8;   // pre-swizzled global col
  }
  int sidB[4], rB[4], cB[4];
#pragma unroll
  for (int j = 0; j < 4; j++) {
    sidB[j] = j * 256 + tid;
    rB[j] = sidB[j] >> 3;
    cB[j] = ((sidB[j] & 7) ^ (rB[j] & 7)) * 8;
  }
  const bf16_t* Abase = A + (size_t)bm0 * lda;
  const bf16_t* Bbase = Bseg + (size_t)bn_loc * ldb;

  f32x4 acc[2][4];
#pragma unroll
  for (int i = 0; i < 2; i++)
#pragma unroll
    for (int j = 0; j < 4; j++) acc[i][j] = f32x4{0.f, 0.f, 0.f, 0.f};

  const int NT = K / BK;

#define STAGE_TILE(t, buf)                                                      \
  do {                                                                          \
    const int koff = (t) * BK;                                                  \
    _Pragma("unroll")                                                           \
    for (int j = 0; j < 2; j++)                                                 \
      ASYNC16(Abase + (size_t)rA[j] * lda + koff + cA[j], &As[buf][sidA[j] * 8]); \
    _Pragma("unroll")                                                           \
    for (int j = 0; j < 4; j++)                                                 \
      ASYNC16(Bbase + (size_t)rB[j] * ldb + koff + cB[j], &Bs[buf][sidB[j] * 8]); \
  } while (0)

  // prologue: tiles 0 and 1 in flight
  STAGE_TILE(0, 0);
  STAGE_TILE(1, 1);

  for (int t = 0; t < NT; ++t) {
    const int cur = t % 3;
    if (t + 1 < NT) asm volatile("s_waitcnt vmcnt(6)" ::: "memory");
    else            asm volatile("s_waitcnt vmcnt(0)" ::: "memory");
    __builtin_amdgcn_s_barrier();
    __builtin_amdgcn_sched_barrier(0);
    if (t + 2 < NT) STAGE_TILE(t + 2, (t + 2) % 3);

#pragma unroll
    for (int kb = 0; kb < 2; kb++) {
      bf16x8 af[2], bfr[4];
#pragma unroll
      for (int mt = 0; mt < 2; mt++) {
        const int r = wr * 32 + mt * 16 + lm;
        af[mt] = *(const bf16x8*)&As[cur][r * 64 + (((kb * 4 + quad) ^ (r & 7)) * 8)];
      }
#pragma unroll
      for (int nt = 0; nt < 4; nt++) {
        const int r = wc * 64 + nt * 16 + lm;
        bfr[nt] = *(const bf16x8*)&Bs[cur][r * 64 + (((kb * 4 + quad) ^ (r & 7)) * 8)];
      }
#pragma unroll
      for (int mt = 0; mt < 2; mt++)
#pragma unroll
        for (int nt = 0; nt < 4; nt++)
          acc[mt][nt] = mfma16(af[mt], bfr[nt], acc[mt][nt]);
    }
  }
#undef STAGE_TILE

#pragma unroll
  for (int mt = 0; mt < 2; mt++) {
#pragma unroll
    for (int nt = 0; nt < 4; nt++) {
      const int row = bm0 + wr * 32 + mt * 16 + quad * 4;
      const int col = bn0 + wc * 64 + nt * 16 + lm;
#pragma unroll
      for (int r = 0; r < 4; r++) {
        if constexpr (C_F32)
          ((float*)Cptr)[(size_t)(row + r) * ldc + col] = acc[mt][nt][r];
        else
          ((bf16_t*)Cptr)[(size_t)(row + r) * ldc + col] = (bf16_t)acc[mt][nt][r];
      }
    }
  }
}

// ======================================================================
// Dequant past K -> fragment-contiguous Kc.
// ======================================================================
__global__ __launch_bounds__(128) void dequant_key(
    const float* __restrict__ pk, bf16_t* __restrict__ Kc)
{
  const int g = blockIdx.x, h = blockIdx.y, d = threadIdx.x;
  const float* src = pk + ((size_t)h * PAST_ + g * 32) * HD_ + d;
  float x[32];
  float mn = 1e30f, mx = -1e30f;
#pragma unroll
  for (int s = 0; s < 32; s++) {
    x[s] = src[(size_t)s * HD_];
    mn = fminf(mn, x[s]); mx = fmaxf(mx, x[s]);
  }
  float scale = (mx - mn) / 15.0f;
  bf16_t* dst = Kc + (size_t)h * (KVL_ * HD_);
#pragma unroll
  for (int s = 0; s < 32; s++) {
    float t = scale > 0.f ? (x[s] - mn) / scale : 0.f;
    float q = fminf(fmaxf(rintf(t), 0.f), 15.f);
    dst[kidx(g * 32 + s, d)] = (bf16_t)(q * scale + mn);
  }
}

// ======================================================================
// Dequant past V -> fragment-contiguous Vc.
// ======================================================================
__global__ __launch_bounds__(256) void dequant_value(
    const float* __restrict__ pv, bf16_t* __restrict__ Vc)
{
  const int sc = blockIdx.x, h = blockIdx.y;
  const int j = threadIdx.x >> 6, lane = threadIdx.x & 63;
  const int s = sc * 64 + lane;
  const float* src = pv + ((size_t)h * PAST_ + s) * HD_ + j * 32;
  float x[32];
  float mn = 1e30f, mx = -1e30f;
#pragma unroll
  for (int q4 = 0; q4 < 8; q4++) {
    float4 f = ((const float4*)src)[q4];
    x[q4*4+0] = f.x; x[q4*4+1] = f.y; x[q4*4+2] = f.z; x[q4*4+3] = f.w;
    mn = fminf(fminf(mn, fminf(f.x, f.y)), fminf(f.z, f.w));
    mx = fmaxf(fmaxf(mx, fmaxf(f.x, f.y)), fmaxf(f.z, f.w));
  }
  float scale = (mx - mn) / 15.0f;
  bf16_t* dst = Vc + (size_t)h * (KVL_ * HD_);
#pragma unroll
  for (int d = 0; d < 32; d++) {
    float t = scale > 0.f ? (x[d] - mn) / scale : 0.f;
    float q = fminf(fmaxf(rintf(t), 0.f), 15.f);
    dst[vidx(s, j * 32 + d)] = (bf16_t)(q * scale + mn);
  }
}

// ======================================================================
// RoPE Q/K_new + scatter into Qa (rows) and Kc/Vc (fragment layout).
// ======================================================================
__global__ __launch_bounds__(128) void rope_scatter(
    const bf16_t* __restrict__ Y, const int* __restrict__ posids,
    bf16_t* __restrict__ Qa, bf16_t* __restrict__ Kc, bf16_t* __restrict__ Vc)
{
  const int i = blockIdx.x;
  const int u = blockIdx.y;
  const int d = threadIdx.x;

  if (u >= 40) {
    const int hv = u - 40;
    float v = (float)Y[(size_t)i * 6144 + 5120 + hv * HD_ + d];
    Vc[(size_t)hv * (KVL_ * HD_) + vidx(PAST_ + i, d)] = (bf16_t)v;
    return;
  }
  const int pos = posids[i];
  const int fi = d & 63;
  const float inv_freq = exp2f(-(float)fi * 0.2076205059304601f);
  const float ang = (float)pos * inv_freq;
  float sn, cs;
  sincosf(ang, &sn, &cs);

  if (u < 32) {
    const bf16_t* src = &Y[(size_t)i * 6144 + u * HD_];
    float x  = (float)src[d];
    float xo = (float)src[d ^ 64];
    float rot = (d < 64) ? -xo : xo;
    Qa[((size_t)u * QL_ + i) * HD_ + d] = (bf16_t)((x * cs + rot * sn) * QSCALE);
  } else {
    const int hk = u - 32;
    const bf16_t* src = &Y[(size_t)i * 6144 + 4096 + hk * HD_];
    float x  = (float)src[d];
    float xo = (float)src[d ^ 64];
    float rot = (d < 64) ? -xo : xo;
    Kc[(size_t)hk * (KVL_ * HD_) + kidx(PAST_ + i, d)] = (bf16_t)(x * cs + rot * sn);
  }
}

// ======================================================================
// Flash attention, ping-pong staged: K(t+1) is issued right after the
// post-QK barrier (flies during PV); V(t+1) right after the post-PV
// barrier (flies during the next QK^T). Same 2 barriers/iter as before
// but staging latency is hidden behind the opposite phase's compute.
// Zero extra LDS -> still 3 blocks/CU.
// ======================================================================
__global__ __launch_bounds__(256, 3) void attn_kernel(
    const bf16_t* __restrict__ Qa, const bf16_t* __restrict__ Kc,
    const bf16_t* __restrict__ Vc, bf16_t* __restrict__ Opart,
    float* __restrict__ ML)
{
  __shared__ bf16_t Ks[64 * HD_];     // 16 KB, fragment-contiguous
  __shared__ bf16_t Vs[64 * HD_];     // 16 KB
  __shared__ bf16_t Pw[4][32 * 64];   // per-wave P scratch, swizzled

  const int tid = threadIdx.x, w = tid >> 6, lane = tid & 63;
  const int lm = lane & 15, quad = lane >> 4;
  const int idx = blockIdx.x;
  const int grp = idx & 63;          // sp*8 + kvh
  const int inner = idx >> 6;        // qt*4 + qh
  const int sp = grp >> 3, kvh = grp & 7;
  const int h = kvh * 4 + (inner & 3);
  const int qt = inner >> 2;
  const int qw = qt * 128 + w * 32;

  bf16x8 ones8;
#pragma unroll
  for (int j = 0; j < 8; j++) ones8[j] = (bf16_t)1.0f;

  bf16x8 qf[2][4];
#pragma unroll
  for (int mt = 0; mt < 2; mt++)
#pragma unroll
    for (int kb = 0; kb < 4; kb++)
      qf[mt][kb] = *(const bf16x8*)&Qa[((size_t)h * QL_ + qw + mt * 16 + lm) * HD_ + kb * 32 + quad * 8];

  f32x4 o[2][8], ol[2];
#pragma unroll
  for (int mt = 0; mt < 2; mt++) {
    ol[mt] = f32x4{0.f, 0.f, 0.f, 0.f};
#pragma unroll
    for (int i = 0; i < 8; i++) o[mt][i] = f32x4{0.f, 0.f, 0.f, 0.f};
  }

  const bf16_t* Kb = Kc + (size_t)kvh * (KVL_ * HD_);
  const bf16_t* Vb = Vc + (size_t)kvh * (KVL_ * HD_);

  const int T = 58 + 2 * qt;
  const int t0 = sp * T / NSPLIT;
  const int t1 = (sp + 1) * T / NSPLIT;

  // prologue: stage K(t0) + V(t0)
  {
    const bf16_t* kt = Kb + (size_t)t0 * 8192;
    const bf16_t* vt = Vb + (size_t)t0 * 8192;
#pragma unroll
    for (int j = 0; j < 4; j++) {
      ASYNC16(kt + (size_t)(tid + j * 256) * 8, &Ks[(tid + j * 256) * 8]);
      ASYNC16(vt + (size_t)(tid + j * 256) * 8, &Vs[(tid + j * 256) * 8]);
    }
  }
  __syncthreads();   // K(t0), V(t0) ready

  for (int it = t0; it < t1; ++it) {
    const bool needmask = (it >= T - 2);
    const int kv0 = it * 64;

    // ---- phase 1: S = Q K^T ; exp2 -> Pw  (reads Ks) ----
#pragma unroll
    for (int nt = 0; nt < 4; nt++) {
      f32x4 s0 = f32x4{0.f, 0.f, 0.f, 0.f};
      f32x4 s1 = f32x4{0.f, 0.f, 0.f, 0.f};
#pragma unroll
      for (int kb = 0; kb < 4; kb++) {
        bf16x8 kf = *(const bf16x8*)&Ks[((nt * 4 + kb) * 64 + lane) * 8];
        s0 = mfma16(qf[0][kb], kf, s0);
        s1 = mfma16(qf[1][kb], kf, s1);
      }
      if (needmask) {
        const int col = kv0 + nt * 16 + lm;
#pragma unroll
        for (int r = 0; r < 4; r++) {
          if (col > PAST_ + qw + quad * 4 + r)      s0[r] = -1e30f;
          if (col > PAST_ + qw + 16 + quad * 4 + r) s1[r] = -1e30f;
        }
      }
#pragma unroll
      for (int r = 0; r < 4; r++) {
        const int row0 = quad * 4 + r;
        const int sg0 = ((nt * 2) + (lm >> 3)) ^ (row0 & 7);
        Pw[w][row0 * 64 + sg0 * 8 + (lm & 7)] = (bf16_t)exp2f(s0[r]);
        const int row1 = 16 + quad * 4 + r;
        const int sg1 = ((nt * 2) + (lm >> 3)) ^ (row1 & 7);
        Pw[w][row1 * 64 + sg1 * 8 + (lm & 7)] = (bf16_t)exp2f(s1[r]);
      }
    }

    __syncthreads();   // all waves done reading Ks (also drains V(it))

    // stage K(it+1): overlaps the PV phase below
    if (it + 1 < t1) {
      const bf16_t* kt = Kb + (size_t)(it + 1) * 8192;
#pragma unroll
      for (int j = 0; j < 4; j++)
        ASYNC16(kt + (size_t)(tid + j * 256) * 8, &Ks[(tid + j * 256) * 8]);
    }

    // ---- phase 2: O += P V  (reads Pw wave-private + Vs) ----
    bf16x8 pf[2][2];
#pragma unroll
    for (int mt = 0; mt < 2; mt++)
#pragma unroll
      for (int kb = 0; kb < 2; kb++) {
        const int r = mt * 16 + lm;
        pf[mt][kb] = *(const bf16x8*)&Pw[w][r * 64 + (((kb * 4 + quad) ^ (r & 7)) * 8)];
      }
#pragma unroll
    for (int dt = 0; dt < 8; dt++) {
#pragma unroll
      for (int kb = 0; kb < 2; kb++) {
        bf16x8 vf = *(const bf16x8*)&Vs[((dt * 2 + kb) * 64 + lane) * 8];
        o[0][dt] = mfma16(pf[0][kb], vf, o[0][dt]);
        o[1][dt] = mfma16(pf[1][kb], vf, o[1][dt]);
      }
    }
#pragma unroll
    for (int kb = 0; kb < 2; kb++) {
      ol[0] = mfma16(pf[0][kb], ones8, ol[0]);
      ol[1] = mfma16(pf[1][kb], ones8, ol[1]);
    }

    __syncthreads();   // all waves done reading Vs; drains K(it+1)

    // stage V(it+1): overlaps the next iteration's QK^T phase
    if (it + 1 < t1) {
      const bf16_t* vt = Vb + (size_t)(it + 1) * 8192;
#pragma unroll
      for (int j = 0; j < 4; j++)
        ASYNC16(vt + (size_t)(tid + j * 256) * 8, &Vs[(tid + j * 256) * 8]);
    }
  }

  // epilogue: un-normalized partial O + l
  const size_t pbase = ((size_t)(sp * NH_ + h) * QL_ + qw);
#pragma unroll
  for (int mt = 0; mt < 2; mt++) {
#pragma unroll
    for (int dt = 0; dt < 8; dt++)
#pragma unroll
      for (int r = 0; r < 4; r++)
        Opart[(pbase + mt * 16 + quad * 4 + r) * HD_ + dt * 16 + lm] = (bf16_t)o[mt][dt][r];
  }
  if (lm == 0) {
#pragma unroll
    for (int mt = 0; mt < 2; mt++)
#pragma unroll
      for (int r = 0; r < 4; r++)
        ML[pbase + mt * 16 + quad * 4 + r] = ol[mt][r];
  }
}

// ======================================================================
// Combine split partials: O = sum_s O_s / sum_s l_s
// ======================================================================
__global__ __launch_bounds__(128) void combine_kernel(
    const bf16_t* __restrict__ Opart, const float* __restrict__ ML,
    bf16_t* __restrict__ AttnO)
{
  const int q = blockIdx.x, h = blockIdx.y, d = threadIdx.x;
  float lsum = 0.f, o = 0.f;
#pragma unroll
  for (int s = 0; s < NSPLIT; s++) {
    const size_t base = (size_t)(s * NH_ + h) * QL_ + q;
    lsum += ML[base];
    o += (float)Opart[base * HD_ + d];
  }
  AttnO[(size_t)q * (NH_ * HD_) + h * HD_ + d] = (bf16_t)(o / lsum);
}

// ======================================================================
extern "C" void kernel_launch(void* const* d_in, const int* in_sizes, int n_in,
                              void* d_out, int out_size, void* d_ws, size_t ws_size,
                              hipStream_t stream)
{
  (void)in_sizes; (void)n_in; (void)out_size; (void)ws_size;
  const float* hidden = (const float*)d_in[0];
  const float* past_k = (const float*)d_in[1];
  const float* past_v = (const float*)d_in[2];
  const float* wq  = (const float*)d_in[3];
  const float* wk  = (const float*)d_in[4];
  const float* wv  = (const float*)d_in[5];
  const float* wo  = (const float*)d_in[6];
  const int*   pos = (const int*)d_in[7];

  char* p = (char*)d_ws;
  bf16_t* Y     = (bf16_t*)p;  p += (size_t)QL_ * 6144 * 2;
  bf16_t* Qa    = (bf16_t*)p;  p += (size_t)QL_ * NH_ * HD_ * 2;
  bf16_t* Kc    = (bf16_t*)p;  p += (size_t)NKV_ * KVL_ * HD_ * 2;
  bf16_t* Vc    = (bf16_t*)p;  p += (size_t)NKV_ * HD_ * KVL_ * 2;
  bf16_t* AttnO = (bf16_t*)p;  p += (size_t)QL_ * NH_ * HD_ * 2;
  bf16_t* Opart = (bf16_t*)p;  p += (size_t)NSPLIT * NH_ * QL_ * HD_ * 2;
  float*  ML    = (float*)p;   p += (size_t)NSPLIT * NH_ * QL_ * 4;
  bf16_t* Hbf   = (bf16_t*)p;  p += (size_t)QL_ * HID_ * 2;
  bf16_t* Wbuf  = (bf16_t*)p;  p += (size_t)4096 * HID_ * 2;   // wq, later wo
  bf16_t* Wkbf  = (bf16_t*)p;  p += (size_t)1024 * HID_ * 2;
  bf16_t* Wvbf  = (bf16_t*)p;  p += (size_t)1024 * HID_ * 2;

  // one fused, load-balanced launch converts wq/wk/wv/hidden
  cvt_multi<<<dim3(2048), 256, 0, stream>>>(wq, wk, wv, hidden,
                                            Wbuf, Wkbf, Wvbf, Hbf);
  dequant_key  <<<dim3(PAST_ / 32, NKV_), dim3(128), 0, stream>>>(past_k, Kc);
  dequant_value<<<dim3(PAST_ / 64, NKV_), dim3(256), 0, stream>>>(past_v, Vc);

  gemm_bt<false><<<dim3(6144 / 128, QL_ / 64), dim3(256), 0, stream>>>(
      Hbf, Wbuf, Wkbf, Wvbf, 4096, 5120, (void*)Y, HID_, HID_, HID_, 6144);

  // wq dead -> reuse Wbuf for wo (stream-ordered after QKV gemm)
  cvt_f32_bf16<<<1024, 256, 0, stream>>>(wo, Wbuf, HID_ * 4096 / 4);

  rope_scatter<<<dim3(QL_, 48), dim3(128), 0, stream>>>(Y, pos, Qa, Kc, Vc);
  attn_kernel <<<dim3(16 * 64), dim3(256), 0, stream>>>(Qa, Kc, Vc, Opart, ML);
  combine_kernel<<<dim3(QL_, NH_), dim3(128), 0, stream>>>(Opart, ML, AttnO);

  gemm_bt<true><<<dim3(4096 / 128, QL_ / 64), dim3(256), 0, stream>>>(
      AttnO, Wbuf, Wbuf, Wbuf, 1 << 30, 1 << 30, d_out,
      NH_ * HD_, NH_ * HD_, HID_, HID_);
}

// Round 5
// 353.750 us; speedup vs baseline: 1.0998x; 1.0998x over previous
//
#include <hip/hip_runtime.h>
#include <hip/hip_bf16.h>

typedef __bf16 bf16_t;
typedef __bf16 bf16x4 __attribute__((ext_vector_type(4)));
typedef __bf16 bf16x8 __attribute__((ext_vector_type(8)));
typedef float  f32x4  __attribute__((ext_vector_type(4)));

static __device__ __forceinline__ f32x4 mfma16(bf16x8 a, bf16x8 b, f32x4 c) {
  return __builtin_amdgcn_mfma_f32_16x16x32_bf16(a, b, c, 0, 0, 0);
}

typedef const __attribute__((address_space(1))) void* gas_t;
typedef __attribute__((address_space(3))) void* las_t;
#define ASYNC16(g, l) __builtin_amdgcn_global_load_lds((gas_t)(g), (las_t)(l), 16, 0, 0)

// Problem constants
#define QL_   512
#define HID_  4096
#define NH_   32
#define NKV_  8
#define HD_   128
#define PAST_ 3584
#define KVL_  4096   // PAST_ + QL_
#define NSPLIT 8     // attention kv-split factor

// Q prescale: log2(e)/sqrt(128) -> softmax via raw exp2, no max subtraction
#define QSCALE 0.12751750152134056f

// K fragment-layout index (kv-tiles of 64, MFMA B-operand contiguous)
static __device__ __forceinline__ size_t kidx(int s, int d) {
  return ((size_t)(((s >> 6) * 4 + ((s >> 4) & 3)) * 4 + (d >> 5))) * 512
         + ((((d >> 3) & 3) * 16 + (s & 15)) * 8) + (d & 7);
}
// V fragment-layout index (PV B-operand: out-col = d, contraction = kv)
static __device__ __forceinline__ size_t vidx(int s, int d) {
  return ((size_t)(((s >> 6) * 8 + (d >> 4)) * 2 + ((s >> 5) & 1))) * 512
         + (((((s >> 3) & 3) * 16 + (d & 15)) * 8)) + (s & 7);
}

// ======================================================================
// fp32 -> bf16 streaming convert (n4 = element count / 4)
// ======================================================================
__global__ __launch_bounds__(256) void cvt_f32_bf16(
    const float* __restrict__ src, bf16_t* __restrict__ dst, int n4)
{
  int i = blockIdx.x * 256 + threadIdx.x;
  const int stride = gridDim.x * 256;
  for (; i < n4; i += stride) {
    float4 f = ((const float4*)src)[i];
    bf16x4 o;
    o[0] = (bf16_t)f.x; o[1] = (bf16_t)f.y; o[2] = (bf16_t)f.z; o[3] = (bf16_t)f.w;
    ((bf16x4*)dst)[i] = o;
  }
}

// Fused convert: wq|wk|wv|hidden in ONE flat index space (load-balanced).
__global__ __launch_bounds__(256) void cvt_multi(
    const float* __restrict__ swq, const float* __restrict__ swk,
    const float* __restrict__ swv, const float* __restrict__ shid,
    bf16_t* __restrict__ dwq, bf16_t* __restrict__ dwk,
    bf16_t* __restrict__ dwv, bf16_t* __restrict__ dhid)
{
  constexpr int N0 = 4096 * HID_ / 4;          // wq  : 4,194,304
  constexpr int N1 = N0 + 1024 * HID_ / 4;     // +wk : 5,242,880
  constexpr int N2 = N1 + 1024 * HID_ / 4;     // +wv : 6,291,456
  constexpr int N3 = N2 + QL_ * HID_ / 4;      // +hid: 6,815,744
  int i = blockIdx.x * 256 + threadIdx.x;
  const int stride = gridDim.x * 256;
  for (; i < N3; i += stride) {
    const float* src; bf16_t* dst; int off;
    if (i < N0)      { src = swq;  dst = dwq;  off = i; }
    else if (i < N1) { src = swk;  dst = dwk;  off = i - N0; }
    else if (i < N2) { src = swv;  dst = dwv;  off = i - N1; }
    else             { src = shid; dst = dhid; off = i - N2; }
    float4 f = ((const float4*)src)[off];
    bf16x4 o;
    o[0] = (bf16_t)f.x; o[1] = (bf16_t)f.y; o[2] = (bf16_t)f.z; o[3] = (bf16_t)f.w;
    ((bf16x4*)dst)[off] = o;
  }
}

// ======================================================================
// Split-K GEMM: Cpart[z][M,N] = A[M, zK/2 : (z+1)K/2] @ B^T slice.
// R3's proven 2-buffer __syncthreads schedule (counted-vmcnt experiment
// reverted -- it reproduced m141's sched_barrier regression). Split-K=2
// via blockIdx.z doubles the grid: QKV 768 blocks (3/CU, = the 48 KB LDS
// residency cap), O-proj 512 (2/CU). Co-resident blocks overlap each
// other's barrier drains (m114) -- the thing R4's deeper pipeline could
// not do with 1.5 blocks/CU.
// BM=64, BN=128, BK=64; 4 waves 2x2 (wave tile 32x64). f32 partials.
// ======================================================================
__global__ __launch_bounds__(256) void gemm_bt(
    const bf16_t* __restrict__ A,
    const bf16_t* __restrict__ B0, const bf16_t* __restrict__ B1,
    const bf16_t* __restrict__ B2, int nsplit1, int nsplit2,
    float* __restrict__ Cpart, int K, int lda, int ldb, int ldc,
    int partstride)
{
  constexpr int BM = 64, BN = 128, BK = 64;
  __shared__ bf16_t As[2][BM * BK];   // 2 x 8 KB
  __shared__ bf16_t Bs[2][BN * BK];   // 2 x 16 KB

  const int tid = threadIdx.x;
  const int w = tid >> 6, lane = tid & 63;
  const int lm = lane & 15, quad = lane >> 4;
  const int wr = w >> 1, wc = w & 1;
  const int bm0 = blockIdx.y * BM, bn0 = blockIdx.x * BN;
  const int Khalf = K >> 1;
  const int kbase = blockIdx.z * Khalf;

  const bf16_t* Bseg; int bn_loc;
  if (bn0 < nsplit1)      { Bseg = B0; bn_loc = bn0; }
  else if (bn0 < nsplit2) { Bseg = B1; bn_loc = bn0 - nsplit1; }
  else                    { Bseg = B2; bn_loc = bn0 - nsplit2; }

  // staging units: A = 512 x 16B (2/thread), B = 1024 x 16B (4/thread)
  int sidA[2], rA[2], cA[2];
#pragma unroll
  for (int j = 0; j < 2; j++) {
    sidA[j] = j * 256 + tid;
    rA[j] = sidA[j] >> 3;
    cA[j] = ((sidA[j] & 7) ^ (rA[j] & 7)) * 8;   // pre-swizzled global col
  }
  int sidB[4], rB[4], cB[4];
#pragma unroll
  for (int j = 0; j < 4; j++) {
    sidB[j] = j * 256 + tid;
    rB[j] = sidB[j] >> 3;
    cB[j] = ((sidB[j] & 7) ^ (rB[j] & 7)) * 8;
  }
  const bf16_t* Abase = A + (size_t)bm0 * lda + kbase;
  const bf16_t* Bbase = Bseg + (size_t)bn_loc * ldb + kbase;

  f32x4 acc[2][4];
#pragma unroll
  for (int i = 0; i < 2; i++)
#pragma unroll
    for (int j = 0; j < 4; j++) acc[i][j] = f32x4{0.f, 0.f, 0.f, 0.f};

  // prologue: stage tile 0
#pragma unroll
  for (int j = 0; j < 2; j++)
    ASYNC16(Abase + (size_t)rA[j] * lda + cA[j], &As[0][sidA[j] * 8]);
#pragma unroll
  for (int j = 0; j < 4; j++)
    ASYNC16(Bbase + (size_t)rB[j] * ldb + cB[j], &Bs[0][sidB[j] * 8]);

  int cur = 0;
  for (int k0 = 0; k0 < Khalf; k0 += BK) {
    __syncthreads();   // single drain point: buf[cur] ready
    if (k0 + BK < Khalf) {
#pragma unroll
      for (int j = 0; j < 2; j++)
        ASYNC16(Abase + (size_t)rA[j] * lda + k0 + BK + cA[j], &As[cur ^ 1][sidA[j] * 8]);
#pragma unroll
      for (int j = 0; j < 4; j++)
        ASYNC16(Bbase + (size_t)rB[j] * ldb + k0 + BK + cB[j], &Bs[cur ^ 1][sidB[j] * 8]);
    }
#pragma unroll
    for (int kb = 0; kb < 2; kb++) {
      bf16x8 af[2], bfr[4];
#pragma unroll
      for (int mt = 0; mt < 2; mt++) {
        const int r = wr * 32 + mt * 16 + lm;
        af[mt] = *(const bf16x8*)&As[cur][r * 64 + (((kb * 4 + quad) ^ (r & 7)) * 8)];
      }
#pragma unroll
      for (int nt = 0; nt < 4; nt++) {
        const int r = wc * 64 + nt * 16 + lm;
        bfr[nt] = *(const bf16x8*)&Bs[cur][r * 64 + (((kb * 4 + quad) ^ (r & 7)) * 8)];
      }
#pragma unroll
      for (int mt = 0; mt < 2; mt++)
#pragma unroll
        for (int nt = 0; nt < 4; nt++)
          acc[mt][nt] = mfma16(af[mt], bfr[nt], acc[mt][nt]);
    }
    cur ^= 1;
  }

  float* Cp = Cpart + (size_t)blockIdx.z * partstride;
#pragma unroll
  for (int mt = 0; mt < 2; mt++) {
#pragma unroll
    for (int nt = 0; nt < 4; nt++) {
      const int row = bm0 + wr * 32 + mt * 16 + quad * 4;
      const int col = bn0 + wc * 64 + nt * 16 + lm;
#pragma unroll
      for (int r = 0; r < 4; r++)
        Cp[(size_t)(row + r) * ldc + col] = acc[mt][nt][r];
    }
  }
}

// O-projection split-K combine: out = P[0] + P[1]  (f32, 512x4096)
__global__ __launch_bounds__(256) void combine_oproj(
    const float* __restrict__ P, float* __restrict__ out)
{
  constexpr int N4 = QL_ * HID_ / 4;   // 524288 float4s
  const int i = blockIdx.x * 256 + threadIdx.x;
  if (i < N4) {
    float4 a = ((const float4*)P)[i];
    float4 b = ((const float4*)P)[N4 + i];
    float4 o; o.x = a.x + b.x; o.y = a.y + b.y; o.z = a.z + b.z; o.w = a.w + b.w;
    ((float4*)out)[i] = o;
  }
}

// ======================================================================
// Dequant past K -> fragment-contiguous Kc.
// ======================================================================
__global__ __launch_bounds__(128) void dequant_key(
    const float* __restrict__ pk, bf16_t* __restrict__ Kc)
{
  const int g = blockIdx.x, h = blockIdx.y, d = threadIdx.x;
  const float* src = pk + ((size_t)h * PAST_ + g * 32) * HD_ + d;
  float x[32];
  float mn = 1e30f, mx = -1e30f;
#pragma unroll
  for (int s = 0; s < 32; s++) {
    x[s] = src[(size_t)s * HD_];
    mn = fminf(mn, x[s]); mx = fmaxf(mx, x[s]);
  }
  float scale = (mx - mn) / 15.0f;
  bf16_t* dst = Kc + (size_t)h * (KVL_ * HD_);
#pragma unroll
  for (int s = 0; s < 32; s++) {
    float t = scale > 0.f ? (x[s] - mn) / scale : 0.f;
    float q = fminf(fmaxf(rintf(t), 0.f), 15.f);
    dst[kidx(g * 32 + s, d)] = (bf16_t)(q * scale + mn);
  }
}

// ======================================================================
// Dequant past V -> fragment-contiguous Vc.
// ======================================================================
__global__ __launch_bounds__(256) void dequant_value(
    const float* __restrict__ pv, bf16_t* __restrict__ Vc)
{
  const int sc = blockIdx.x, h = blockIdx.y;
  const int j = threadIdx.x >> 6, lane = threadIdx.x & 63;
  const int s = sc * 64 + lane;
  const float* src = pv + ((size_t)h * PAST_ + s) * HD_ + j * 32;
  float x[32];
  float mn = 1e30f, mx = -1e30f;
#pragma unroll
  for (int q4 = 0; q4 < 8; q4++) {
    float4 f = ((const float4*)src)[q4];
    x[q4*4+0] = f.x; x[q4*4+1] = f.y; x[q4*4+2] = f.z; x[q4*4+3] = f.w;
    mn = fminf(fminf(mn, fminf(f.x, f.y)), fminf(f.z, f.w));
    mx = fmaxf(fmaxf(mx, fmaxf(f.x, f.y)), fmaxf(f.z, f.w));
  }
  float scale = (mx - mn) / 15.0f;
  bf16_t* dst = Vc + (size_t)h * (KVL_ * HD_);
#pragma unroll
  for (int d = 0; d < 32; d++) {
    float t = scale > 0.f ? (x[d] - mn) / scale : 0.f;
    float q = fminf(fmaxf(rintf(t), 0.f), 15.f);
    dst[vidx(s, j * 32 + d)] = (bf16_t)(q * scale + mn);
  }
}

// ======================================================================
// RoPE Q/K_new + scatter into Qa (rows) and Kc/Vc (fragment layout).
// Now also the split-K combine for the QKV projection: reads the two
// f32 partials of Y and sums them inline (no separate combine pass).
// ======================================================================
__global__ __launch_bounds__(128) void rope_scatter(
    const float* __restrict__ Yp, const int* __restrict__ posids,
    bf16_t* __restrict__ Qa, bf16_t* __restrict__ Kc, bf16_t* __restrict__ Vc)
{
  const int i = blockIdx.x;
  const int u = blockIdx.y;
  const int d = threadIdx.x;
  const size_t b0 = (size_t)i * 6144;
  const size_t b1 = b0 + (size_t)QL_ * 6144;

  if (u >= 40) {
    const int hv = u - 40;
    const int c = 5120 + hv * HD_ + d;
    float v = Yp[b0 + c] + Yp[b1 + c];
    Vc[(size_t)hv * (KVL_ * HD_) + vidx(PAST_ + i, d)] = (bf16_t)v;
    return;
  }
  const int pos = posids[i];
  const int fi = d & 63;
  const float inv_freq = exp2f(-(float)fi * 0.2076205059304601f);
  const float ang = (float)pos * inv_freq;
  float sn, cs;
  sincosf(ang, &sn, &cs);

  if (u < 32) {
    const int c = u * HD_;
    float x  = Yp[b0 + c + d] + Yp[b1 + c + d];
    float xo = Yp[b0 + c + (d ^ 64)] + Yp[b1 + c + (d ^ 64)];
    float rot = (d < 64) ? -xo : xo;
    Qa[((size_t)u * QL_ + i) * HD_ + d] = (bf16_t)((x * cs + rot * sn) * QSCALE);
  } else {
    const int hk = u - 32;
    const int c = 4096 + hk * HD_;
    float x  = Yp[b0 + c + d] + Yp[b1 + c + d];
    float xo = Yp[b0 + c + (d ^ 64)] + Yp[b1 + c + (d ^ 64)];
    float rot = (d < 64) ? -xo : xo;
    Kc[(size_t)hk * (KVL_ * HD_) + kidx(PAST_ + i, d)] = (bf16_t)(x * cs + rot * sn);
  }
}

// ======================================================================
// Flash attention, ping-pong staged (unchanged from R3; it helped).
// ======================================================================
__global__ __launch_bounds__(256, 3) void attn_kernel(
    const bf16_t* __restrict__ Qa, const bf16_t* __restrict__ Kc,
    const bf16_t* __restrict__ Vc, bf16_t* __restrict__ Opart,
    float* __restrict__ ML)
{
  __shared__ bf16_t Ks[64 * HD_];     // 16 KB, fragment-contiguous
  __shared__ bf16_t Vs[64 * HD_];     // 16 KB
  __shared__ bf16_t Pw[4][32 * 64];   // per-wave P scratch, swizzled

  const int tid = threadIdx.x, w = tid >> 6, lane = tid & 63;
  const int lm = lane & 15, quad = lane >> 4;
  const int idx = blockIdx.x;
  const int grp = idx & 63;          // sp*8 + kvh
  const int inner = idx >> 6;        // qt*4 + qh
  const int sp = grp >> 3, kvh = grp & 7;
  const int h = kvh * 4 + (inner & 3);
  const int qt = inner >> 2;
  const int qw = qt * 128 + w * 32;

  bf16x8 ones8;
#pragma unroll
  for (int j = 0; j < 8; j++) ones8[j] = (bf16_t)1.0f;

  bf16x8 qf[2][4];
#pragma unroll
  for (int mt = 0; mt < 2; mt++)
#pragma unroll
    for (int kb = 0; kb < 4; kb++)
      qf[mt][kb] = *(const bf16x8*)&Qa[((size_t)h * QL_ + qw + mt * 16 + lm) * HD_ + kb * 32 + quad * 8];

  f32x4 o[2][8], ol[2];
#pragma unroll
  for (int mt = 0; mt < 2; mt++) {
    ol[mt] = f32x4{0.f, 0.f, 0.f, 0.f};
#pragma unroll
    for (int i = 0; i < 8; i++) o[mt][i] = f32x4{0.f, 0.f, 0.f, 0.f};
  }

  const bf16_t* Kb = Kc + (size_t)kvh * (KVL_ * HD_);
  const bf16_t* Vb = Vc + (size_t)kvh * (KVL_ * HD_);

  const int T = 58 + 2 * qt;
  const int t0 = sp * T / NSPLIT;
  const int t1 = (sp + 1) * T / NSPLIT;

  // prologue: stage K(t0) + V(t0)
  {
    const bf16_t* kt = Kb + (size_t)t0 * 8192;
    const bf16_t* vt = Vb + (size_t)t0 * 8192;
#pragma unroll
    for (int j = 0; j < 4; j++) {
      ASYNC16(kt + (size_t)(tid + j * 256) * 8, &Ks[(tid + j * 256) * 8]);
      ASYNC16(vt + (size_t)(tid + j * 256) * 8, &Vs[(tid + j * 256) * 8]);
    }
  }
  __syncthreads();   // K(t0), V(t0) ready

  for (int it = t0; it < t1; ++it) {
    const bool needmask = (it >= T - 2);
    const int kv0 = it * 64;

    // ---- phase 1: S = Q K^T ; exp2 -> Pw  (reads Ks) ----
#pragma unroll
    for (int nt = 0; nt < 4; nt++) {
      f32x4 s0 = f32x4{0.f, 0.f, 0.f, 0.f};
      f32x4 s1 = f32x4{0.f, 0.f, 0.f, 0.f};
#pragma unroll
      for (int kb = 0; kb < 4; kb++) {
        bf16x8 kf = *(const bf16x8*)&Ks[((nt * 4 + kb) * 64 + lane) * 8];
        s0 = mfma16(qf[0][kb], kf, s0);
        s1 = mfma16(qf[1][kb], kf, s1);
      }
      if (needmask) {
        const int col = kv0 + nt * 16 + lm;
#pragma unroll
        for (int r = 0; r < 4; r++) {
          if (col > PAST_ + qw + quad * 4 + r)      s0[r] = -1e30f;
          if (col > PAST_ + qw + 16 + quad * 4 + r) s1[r] = -1e30f;
        }
      }
#pragma unroll
      for (int r = 0; r < 4; r++) {
        const int row0 = quad * 4 + r;
        const int sg0 = ((nt * 2) + (lm >> 3)) ^ (row0 & 7);
        Pw[w][row0 * 64 + sg0 * 8 + (lm & 7)] = (bf16_t)exp2f(s0[r]);
        const int row1 = 16 + quad * 4 + r;
        const int sg1 = ((nt * 2) + (lm >> 3)) ^ (row1 & 7);
        Pw[w][row1 * 64 + sg1 * 8 + (lm & 7)] = (bf16_t)exp2f(s1[r]);
      }
    }

    __syncthreads();   // all waves done reading Ks (also drains V(it))

    // stage K(it+1): overlaps the PV phase below
    if (it + 1 < t1) {
      const bf16_t* kt = Kb + (size_t)(it + 1) * 8192;
#pragma unroll
      for (int j = 0; j < 4; j++)
        ASYNC16(kt + (size_t)(tid + j * 256) * 8, &Ks[(tid + j * 256) * 8]);
    }

    // ---- phase 2: O += P V  (reads Pw wave-private + Vs) ----
    bf16x8 pf[2][2];
#pragma unroll
    for (int mt = 0; mt < 2; mt++)
#pragma unroll
      for (int kb = 0; kb < 2; kb++) {
        const int r = mt * 16 + lm;
        pf[mt][kb] = *(const bf16x8*)&Pw[w][r * 64 + (((kb * 4 + quad) ^ (r & 7)) * 8)];
      }
#pragma unroll
    for (int dt = 0; dt < 8; dt++) {
#pragma unroll
      for (int kb = 0; kb < 2; kb++) {
        bf16x8 vf = *(const bf16x8*)&Vs[((dt * 2 + kb) * 64 + lane) * 8];
        o[0][dt] = mfma16(pf[0][kb], vf, o[0][dt]);
        o[1][dt] = mfma16(pf[1][kb], vf, o[1][dt]);
      }
    }
#pragma unroll
    for (int kb = 0; kb < 2; kb++) {
      ol[0] = mfma16(pf[0][kb], ones8, ol[0]);
      ol[1] = mfma16(pf[1][kb], ones8, ol[1]);
    }

    __syncthreads();   // all waves done reading Vs; drains K(it+1)

    // stage V(it+1): overlaps the next iteration's QK^T phase
    if (it + 1 < t1) {
      const bf16_t* vt = Vb + (size_t)(it + 1) * 8192;
#pragma unroll
      for (int j = 0; j < 4; j++)
        ASYNC16(vt + (size_t)(tid + j * 256) * 8, &Vs[(tid + j * 256) * 8]);
    }
  }

  // epilogue: un-normalized partial O + l
  const size_t pbase = ((size_t)(sp * NH_ + h) * QL_ + qw);
#pragma unroll
  for (int mt = 0; mt < 2; mt++) {
#pragma unroll
    for (int dt = 0; dt < 8; dt++)
#pragma unroll
      for (int r = 0; r < 4; r++)
        Opart[(pbase + mt * 16 + quad * 4 + r) * HD_ + dt * 16 + lm] = (bf16_t)o[mt][dt][r];
  }
  if (lm == 0) {
#pragma unroll
    for (int mt = 0; mt < 2; mt++)
#pragma unroll
      for (int r = 0; r < 4; r++)
        ML[pbase + mt * 16 + quad * 4 + r] = ol[mt][r];
  }
}

// ======================================================================
// Combine attention split partials: O = sum_s O_s / sum_s l_s
// ======================================================================
__global__ __launch_bounds__(128) void combine_kernel(
    const bf16_t* __restrict__ Opart, const float* __restrict__ ML,
    bf16_t* __restrict__ AttnO)
{
  const int q = blockIdx.x, h = blockIdx.y, d = threadIdx.x;
  float lsum = 0.f, o = 0.f;
#pragma unroll
  for (int s = 0; s < NSPLIT; s++) {
    const size_t base = (size_t)(s * NH_ + h) * QL_ + q;
    lsum += ML[base];
    o += (float)Opart[base * HD_ + d];
  }
  AttnO[(size_t)q * (NH_ * HD_) + h * HD_ + d] = (bf16_t)(o / lsum);
}

// ======================================================================
extern "C" void kernel_launch(void* const* d_in, const int* in_sizes, int n_in,
                              void* d_out, int out_size, void* d_ws, size_t ws_size,
                              hipStream_t stream)
{
  (void)in_sizes; (void)n_in; (void)out_size; (void)ws_size;
  const float* hidden = (const float*)d_in[0];
  const float* past_k = (const float*)d_in[1];
  const float* past_v = (const float*)d_in[2];
  const float* wq  = (const float*)d_in[3];
  const float* wk  = (const float*)d_in[4];
  const float* wv  = (const float*)d_in[5];
  const float* wo  = (const float*)d_in[6];
  const int*   pos = (const int*)d_in[7];

  char* p = (char*)d_ws;
  // SCRATCH region, time-shared (live ranges disjoint, stream-ordered):
  //   Ypart  f32 [2][512][6144] = 25.2 MB  (QKV out -> rope_scatter)
  //   Opart  bf16 [8][32][512][128] = 33.6 MB (attn -> combine_kernel)
  //   Opart2 f32 [2][512][4096] = 16.8 MB  (O-proj -> combine_oproj)
  float*  Ypart  = (float*)p;
  bf16_t* Opart  = (bf16_t*)p;
  float*  Opart2 = (float*)p;
  p += (size_t)NSPLIT * NH_ * QL_ * HD_ * 2;   // 33.6 MB (largest)
  bf16_t* Qa    = (bf16_t*)p;  p += (size_t)QL_ * NH_ * HD_ * 2;
  bf16_t* Kc    = (bf16_t*)p;  p += (size_t)NKV_ * KVL_ * HD_ * 2;
  bf16_t* Vc    = (bf16_t*)p;  p += (size_t)NKV_ * HD_ * KVL_ * 2;
  bf16_t* AttnO = (bf16_t*)p;  p += (size_t)QL_ * NH_ * HD_ * 2;
  float*  ML    = (float*)p;   p += (size_t)NSPLIT * NH_ * QL_ * 4;
  bf16_t* Hbf   = (bf16_t*)p;  p += (size_t)QL_ * HID_ * 2;
  bf16_t* Wbuf  = (bf16_t*)p;  p += (size_t)4096 * HID_ * 2;   // wq, later wo
  bf16_t* Wkbf  = (bf16_t*)p;  p += (size_t)1024 * HID_ * 2;
  bf16_t* Wvbf  = (bf16_t*)p;  p += (size_t)1024 * HID_ * 2;

  // one fused, load-balanced launch converts wq/wk/wv/hidden
  cvt_multi<<<dim3(2048), 256, 0, stream>>>(wq, wk, wv, hidden,
                                            Wbuf, Wkbf, Wvbf, Hbf);
  dequant_key  <<<dim3(PAST_ / 32, NKV_), dim3(128), 0, stream>>>(past_k, Kc);
  dequant_value<<<dim3(PAST_ / 64, NKV_), dim3(256), 0, stream>>>(past_v, Vc);

  // QKV projection, split-K=2 -> f32 partials Ypart
  gemm_bt<<<dim3(6144 / 128, QL_ / 64, 2), dim3(256), 0, stream>>>(
      Hbf, Wbuf, Wkbf, Wvbf, 4096, 5120, Ypart, HID_, HID_, HID_, 6144,
      QL_ * 6144);

  // wq dead -> reuse Wbuf for wo (stream-ordered after QKV gemm)
  cvt_f32_bf16<<<1024, 256, 0, stream>>>(wo, Wbuf, HID_ * 4096 / 4);

  // rope_scatter fuses the QKV split-K combine (reads both partials)
  rope_scatter<<<dim3(QL_, 48), dim3(128), 0, stream>>>(Ypart, pos, Qa, Kc, Vc);
  attn_kernel <<<dim3(16 * 64), dim3(256), 0, stream>>>(Qa, Kc, Vc, Opart, ML);
  combine_kernel<<<dim3(QL_, NH_), dim3(128), 0, stream>>>(Opart, ML, AttnO);

  // O projection, split-K=2 -> f32 partials Opart2 (aliases dead Opart)
  gemm_bt<<<dim3(4096 / 128, QL_ / 64, 2), dim3(256), 0, stream>>>(
      AttnO, Wbuf, Wbuf, Wbuf, 1 << 30, 1 << 30, Opart2,
      NH_ * HD_, NH_ * HD_, HID_, HID_, QL_ * HID_);
  combine_oproj<<<dim3(QL_ * HID_ / 4 / 256), dim3(256), 0, stream>>>(
      Opart2, (float*)d_out);
}